// Round 8
// baseline (224.255 us; speedup 1.0000x reference)
//
#include <hip/hip_runtime.h>
#include <hip/hip_bf16.h>

// MicroHeadAttention on MI355X (gfx950). fp32 in / fp32 out, bf16 MFMA internally.
// Pipeline: [cvt fp32->bf16] -> [QKV gemm, global_load_lds] -> [transpose_v]
//        -> [attn v5: split-K partials, 1024 blocks = 4/CU] -> [merge] -> [out-proj gemm].
// Packed index i = n*8 + m per (b,g): scrambled head m'=i>>11, pos = i&2047.
// Address of packed row i: (b*2048 + (i>>3))*1024 + g*512 + (i&7)*64.
// Workspace (32 MB): Wb(8: Wq region reused for m/l partials after QKV) | xb(8, ->VT)
//                  | Qb(8, ->Cb) | Kb(8).  O partials + V scratch live in d_out.

typedef unsigned short ushortT;
typedef __attribute__((ext_vector_type(8))) short short8;
typedef __attribute__((ext_vector_type(4))) float floatx4;

__device__ inline float bf2f(ushortT u) {
    union { unsigned int i; float f; } v; v.i = ((unsigned int)u) << 16; return v.f;
}
__device__ inline ushortT f2bf(float f) {
    union { float f; unsigned int i; } v; v.f = f;
    unsigned int x = v.i;
    return (ushortT)((x + 0x7fffu + ((x >> 16) & 1u)) >> 16);  // RNE
}

__device__ inline void gl_lds16(const ushortT* g, ushortT* lds) {
    __builtin_amdgcn_global_load_lds(
        (const __attribute__((address_space(1))) unsigned int*)g,
        (__attribute__((address_space(3))) unsigned int*)lds, 16, 0, 0);
}

// ---------------------------------------------------------------------------
// cvt: x (4M f32) -> xb bf16; Wq,Wk,Wv,Wo (1M each) -> Wb stacked bf16.
// ---------------------------------------------------------------------------
__global__ __launch_bounds__(256) void cvt_bf16(
    const float* __restrict__ x,
    const float* __restrict__ Wq, const float* __restrict__ Wk,
    const float* __restrict__ Wv, const float* __restrict__ Wo,
    ushortT* __restrict__ xb, ushortT* __restrict__ Wb)
{
    const unsigned tid = blockIdx.x * 256 + threadIdx.x;
    const size_t e = (size_t)tid * 8;
    const float* src;
    ushortT* dst;
    size_t off;
    if (e < (size_t)(4u << 20)) { src = x; dst = xb; off = e; }
    else {
        const size_t r = e - (size_t)(4u << 20);
        const int wsel = (int)(r >> 20);
        off = r & 0xFFFFFu;
        src = (wsel == 0) ? Wq : (wsel == 1) ? Wk : (wsel == 2) ? Wv : Wo;
        dst = Wb + ((size_t)wsel << 20);
    }
    const float4 f0 = ((const float4*)(src + off))[0];
    const float4 f1 = ((const float4*)(src + off))[1];
    union { __hip_bfloat162 h[4]; uint4 u; } pk;
    pk.h[0] = __float22bfloat162_rn(float2{f0.x, f0.y});
    pk.h[1] = __float22bfloat162_rn(float2{f0.z, f0.w});
    pk.h[2] = __float22bfloat162_rn(float2{f1.x, f1.y});
    pk.h[3] = __float22bfloat162_rn(float2{f1.z, f1.w});
    *(uint4*)(dst + off) = pk.u;
}

// ---------------------------------------------------------------------------
// gemm_lds: C[m,n] = sum_k A[m,k]*W[n,k] + bias[n]. Pure bf16, global_load_lds
// staging with XOR chunk swizzle. 128x128 tile, BK=64, 4 waves, 4x4 MFMA.
// ---------------------------------------------------------------------------
template <bool OUT_F32>
__global__ __launch_bounds__(256) void gemm_lds(
    const ushortT* __restrict__ A, const ushortT* __restrict__ Wst,
    const float* __restrict__ b0, const float* __restrict__ b1, const float* __restrict__ b2,
    void* __restrict__ O0, void* __restrict__ O1, void* __restrict__ O2)
{
    __shared__ __align__(16) ushortT As[128 * 64];
    __shared__ __align__(16) ushortT Bs[128 * 64];
    const int t = threadIdx.x;
    const int m0 = blockIdx.y * 128;
    const int n0g = blockIdx.x * 128;
    const int mat = n0g >> 10;
    const int n0 = n0g & 1023;
    const ushortT* W = Wst + ((size_t)mat << 20);
    const float* bias = (mat == 0) ? b0 : (mat == 1) ? b1 : b2;
    void* Out        = (mat == 0) ? O0 : (mat == 1) ? O1 : O2;

    const int w = t >> 6, lane = t & 63;
    const int wm = w >> 1, wn = w & 1;
    const int col16 = lane & 15, quad = lane >> 4;

    floatx4 acc[4][4];
    for (int i = 0; i < 4; i++)
        for (int j = 0; j < 4; j++) acc[i][j] = (floatx4)0.0f;

    const int cid0 = w * 256 + lane;

    for (int k0 = 0; k0 < 1024; k0 += 64) {
        #pragma unroll
        for (int q = 0; q < 4; q++) {
            const int cid = cid0 + q * 64;
            const int row = cid >> 3;
            const int sch = (cid & 7) ^ (row & 7);
            ushortT* dstA = As + (size_t)(w * 256 + q * 64) * 8;
            ushortT* dstB = Bs + (size_t)(w * 256 + q * 64) * 8;
            gl_lds16(A + (size_t)(m0 + row) * 1024 + k0 + sch * 8, dstA);
            gl_lds16(W + (size_t)(n0 + row) * 1024 + k0 + sch * 8, dstB);
        }
        __syncthreads();
        #pragma unroll
        for (int ks = 0; ks < 64; ks += 32) {
            const int cbase = (ks >> 3) + quad;
            const int sw = col16 & 7;
            short8 a[4], b[4];
            #pragma unroll
            for (int i = 0; i < 4; i++) {
                const int row = wm * 64 + i * 16 + col16;
                a[i] = *(const short8*)(As + row * 64 + ((cbase ^ sw) << 3));
            }
            #pragma unroll
            for (int j = 0; j < 4; j++) {
                const int row = wn * 64 + j * 16 + col16;
                b[j] = *(const short8*)(Bs + row * 64 + ((cbase ^ sw) << 3));
            }
            #pragma unroll
            for (int i = 0; i < 4; i++)
                #pragma unroll
                for (int j = 0; j < 4; j++)
                    acc[i][j] = __builtin_amdgcn_mfma_f32_16x16x32_bf16(a[i], b[j], acc[i][j], 0, 0, 0);
        }
        __syncthreads();
    }

    for (int j = 0; j < 4; j++) {
        const int colg = n0 + wn * 64 + j * 16 + col16;
        const float bv = bias[colg];
        for (int i = 0; i < 4; i++) {
            const int rbase = m0 + wm * 64 + i * 16 + quad * 4;
            for (int r = 0; r < 4; r++) {
                const float val = acc[i][j][r] + bv;
                if constexpr (OUT_F32)
                    ((float*)Out)[(size_t)(rbase + r) * 1024 + colg] = val;
                else
                    ((ushortT*)Out)[(size_t)(rbase + r) * 1024 + colg] = f2bf(val);
            }
        }
    }
}

// ---------------------------------------------------------------------------
// transpose_v: Vb (packed rows) -> VT[slice][d (64)][pos (2048)], slice=(b*2+g)*8+m'.
// ---------------------------------------------------------------------------
__global__ __launch_bounds__(256) void transpose_v(
    const ushortT* __restrict__ Vb, ushortT* __restrict__ VT)
{
    __shared__ ushortT L[64 * 65];
    const int bid = blockIdx.x;
    const int pt = bid & 31, s = bid >> 5;
    const int bb = s >> 4, g = (s >> 3) & 1, mh = s & 7;
    const size_t baseoff = (size_t)bb * 2048 * 1024 + (size_t)g * 512;
    const int t = threadIdx.x;
    {
        const int pr = t >> 2, seg = t & 3;
        const int i = mh * 2048 + pt * 64 + pr;
        const uint4* src = (const uint4*)(Vb + baseoff + (size_t)(i >> 3) * 1024 + (i & 7) * 64 + seg * 16);
        union { uint4 u[2]; ushortT h[16]; } tmp;
        tmp.u[0] = src[0]; tmp.u[1] = src[1];
        #pragma unroll
        for (int d = 0; d < 16; d++) L[pr * 65 + seg * 16 + d] = tmp.h[d];
    }
    __syncthreads();
    {
        const int dc = t >> 2, pseg = t & 3;
        union { uint4 u[2]; ushortT h[16]; } tmp;
        #pragma unroll
        for (int j = 0; j < 16; j++) tmp.h[j] = L[(pseg * 16 + j) * 65 + dc];
        uint4* dst = (uint4*)(VT + (size_t)s * 64 * 2048 + (size_t)dc * 2048 + pt * 64 + pseg * 16);
        dst[0] = tmp.u[0]; dst[1] = tmp.u[1];
    }
}

// ---------------------------------------------------------------------------
// attn v5: split-K flash attention -> unnormalized partials.
// 1024 blocks = xcd(8) x [slice-in-xcd(4) x pair(16) x half(2)] = 4 blocks/CU.
// Pair p: qtA=p, qtB=31-p. K0 = max(8, 16-p): half0 kt in [0,K0) (16-17 iters),
// half1 kt in [K0, qtB] (16-17 iters). Q in registers; transposed softmax
// (queries on col=lane&15, m/l/alpha per-lane scalar); LDS 40 KB.
// Partials: O (bf16) -> OP[slot][tile*64+q][64], m/l (f32) -> ML[slot][tile*64+q].
// No inter-block communication (merge kernel combines) -- G16-safe.
// ---------------------------------------------------------------------------
__global__ __launch_bounds__(256) void attn(
    const ushortT* __restrict__ Qb, const ushortT* __restrict__ Kb,
    const ushortT* __restrict__ VT,
    ushortT* __restrict__ OP, float2* __restrict__ ML)
{
    __shared__ __align__(16) ushortT Ks[2][64 * 64];   // [key][d], chunk-swizzled
    __shared__ __align__(16) ushortT Vs[2][64 * 64];   // [d][key], chunk-swizzled
    __shared__ __align__(16) ushortT Ps[64 * 64];      // [q][key], chunk-swizzled

    const int t = threadIdx.x;
    const int bid = blockIdx.x;
    const int xcd = bid & 7;
    const int jj  = bid >> 3;              // 0..127
    const int s   = xcd * 4 + (jj >> 5);   // 4 slices per XCD
    const int rem = jj & 31;
    const int p   = rem & 15;
    const int half = rem >> 4;
    const int qtA = p, qtB = 31 - p;
    const int K0 = (16 - p > 8) ? (16 - p) : 8;
    const int kts = half ? K0 : 0;
    const int kte = half ? qtB : (K0 - 1);
    const int bb = s >> 4, g = (s >> 3) & 1, mh = s & 7;

    const int w = t >> 6, lane = t & 63;
    const int col16 = lane & 15, quad = lane >> 4;

    const size_t baseoff = (size_t)bb * 2048 * 1024 + (size_t)g * 512;
    const size_t vtbase  = (size_t)s * 64 * 2048;
    const int i0A = mh * 2048 + qtA * 64;
    const int i0B = mh * 2048 + qtB * 64;
    const int qloc = w * 16 + col16;       // this lane's query within a tile
    const int psw = qloc & 7;              // Ps chunk swizzle
    const float KL = 0.125f * 1.44269504f; // scale * log2(e)

    // Q fragments in registers: [tile][ks-half], B-operand layout.
    short8 qreg[2][2];
    {
        const int iA = i0A + qloc, iB = i0B + qloc;
        const ushortT* pA = Qb + baseoff + (size_t)(iA >> 3) * 1024 + (iA & 7) * 64;
        const ushortT* pB = Qb + baseoff + (size_t)(iB >> 3) * 1024 + (iB & 7) * 64;
        qreg[0][0] = *(const short8*)(pA + quad * 8);
        qreg[0][1] = *(const short8*)(pA + 32 + quad * 8);
        qreg[1][0] = *(const short8*)(pB + quad * 8);
        qreg[1][1] = *(const short8*)(pB + 32 + quad * 8);
    }

    auto stageKV = [&](int kt, int bsel) {
        ushortT* kd = &Ks[bsel][0] + (size_t)(w * 128) * 8;
        ushortT* vd = &Vs[bsel][0] + (size_t)(w * 128) * 8;
        #pragma unroll
        for (int q = 0; q < 2; q++) {
            const int cid = w * 128 + q * 64 + lane;
            const int row = cid >> 3;
            const int sch = (cid & 7) ^ (row & 7);
            const int jr = mh * 2048 + kt * 64 + row;
            gl_lds16(Kb + baseoff + (size_t)(jr >> 3) * 1024 + (jr & 7) * 64 + sch * 8,
                     kd + q * 64 * 8);
            gl_lds16(VT + vtbase + (size_t)row * 2048 + kt * 64 + sch * 8,
                     vd + q * 64 * 8);
        }
    };

    float m_s[2] = {-1e30f, -1e30f};
    float l_s[2] = {0.f, 0.f};
    floatx4 Oacc[2][4];
    for (int tl = 0; tl < 2; tl++)
        for (int c = 0; c < 4; c++) Oacc[tl][c] = (floatx4)0.0f;

    stageKV(kts, 0);
    for (int kt = kts; kt <= kte; ++kt) {
        const int bsel = (kt - kts) & 1;
        __syncthreads();                            // vmcnt drained -> buffers ready
        if (kt < kte) stageKV(kt + 1, bsel ^ 1);    // prefetch overlaps compute

        #pragma unroll
        for (int tile = 0; tile < 2; ++tile) {
            const int qt = tile ? qtB : qtA;
            if (kt > qt) continue;                  // wave-uniform

            // S^T = K * Q^T : rows = keys, cols = queries
            floatx4 sc[4];
            for (int c = 0; c < 4; c++) sc[c] = (floatx4)0.0f;
            #pragma unroll
            for (int ks = 0; ks < 32 * 2; ks += 32) {
                const short8 bq = qreg[tile][ks >> 5];
                #pragma unroll
                for (int c = 0; c < 4; c++) {
                    const int krow = c * 16 + col16;
                    const short8 ak = *(const short8*)(&Ks[bsel][0] + krow * 64 +
                                        ((((ks >> 3) + quad) ^ (krow & 7)) << 3));
                    sc[c] = __builtin_amdgcn_mfma_f32_16x16x32_bf16(ak, bq, sc[c], 0, 0, 0);
                }
            }

            // online softmax: lane holds 16 keys of ONE query
            if (kt == qt) {                         // diagonal tile: causal mask
                #pragma unroll
                for (int c = 0; c < 4; c++)
                    #pragma unroll
                    for (int r = 0; r < 4; r++)
                        if ((c * 16 + quad * 4 + r) > qloc) sc[c][r] = -1e30f;
            }
            float mx = -1e30f;
            #pragma unroll
            for (int c = 0; c < 4; c++)
                #pragma unroll
                for (int r = 0; r < 4; r++) mx = fmaxf(mx, sc[c][r]);
            mx = fmaxf(mx, __shfl_xor(mx, 16));
            mx = fmaxf(mx, __shfl_xor(mx, 32));
            const float mold = m_s[tile];
            const float mnew = fmaxf(mold, mx);
            const float alpha = exp2f((mold - mnew) * KL);
            m_s[tile] = mnew;
            const float mKL = mnew * KL;
            float sum = 0.f;
            #pragma unroll
            for (int c = 0; c < 4; c++)
                #pragma unroll
                for (int r = 0; r < 4; r++) {
                    const float pv = exp2f(__builtin_fmaf(sc[c][r], KL, -mKL));
                    sc[c][r] = pv;
                    sum += pv;
                }
            sum += __shfl_xor(sum, 16);
            sum += __shfl_xor(sum, 32);
            l_s[tile] = l_s[tile] * alpha + sum;
            #pragma unroll
            for (int c = 0; c < 4; c++) Oacc[tile][c] *= alpha;

            // P -> Ps[q][key] via packed cvt; per-wave-private rows, no barrier.
            #pragma unroll
            for (int c = 0; c < 4; c++) {
                const int key0 = c * 16 + quad * 4;
                union { __hip_bfloat162 h[2]; unsigned long long u; } pk2;
                pk2.h[0] = __float22bfloat162_rn(float2{sc[c][0], sc[c][1]});
                pk2.h[1] = __float22bfloat162_rn(float2{sc[c][2], sc[c][3]});
                *(unsigned long long*)(Ps + qloc * 64 +
                    (((key0 >> 3) ^ psw) << 3) + (key0 & 7)) = pk2.u;
            }

            // O^T += V^T * P^T : rows = d, cols = queries
            #pragma unroll
            for (int kk = 0; kk < 32 * 2; kk += 32) {
                const short8 bp = *(const short8*)(Ps + qloc * 64 +
                                    ((((kk >> 3) + quad) ^ psw) << 3));
                #pragma unroll
                for (int c = 0; c < 4; c++) {
                    const int drow = c * 16 + col16;
                    const short8 av = *(const short8*)(&Vs[bsel][0] + drow * 64 +
                                        ((((kk >> 3) + quad) ^ (drow & 7)) << 3));
                    Oacc[tile][c] = __builtin_amdgcn_mfma_f32_16x16x32_bf16(av, bp, Oacc[tile][c], 0, 0, 0);
                }
            }
        }
    }

    // write UNNORMALIZED partials: O bf16, (m,l) f32. slot = (s*16+p)*2+half.
    const int slot = ((s * 16 + p) << 1) + half;
    ushortT* od = OP + (size_t)slot * 8192;
    #pragma unroll
    for (int tile = 0; tile < 2; ++tile) {
        ushortT* dst = od + (size_t)(tile * 64 + qloc) * 64;
        #pragma unroll
        for (int c = 0; c < 4; c++) {
            union { __hip_bfloat162 h[2]; unsigned long long u; } pk2;
            pk2.h[0] = __float22bfloat162_rn(float2{Oacc[tile][c][0], Oacc[tile][c][1]});
            pk2.h[1] = __float22bfloat162_rn(float2{Oacc[tile][c][2], Oacc[tile][c][3]});
            *(unsigned long long*)(dst + c * 16 + quad * 4) = pk2.u;
        }
        if (quad == 0)
            ML[(size_t)slot * 128 + tile * 64 + qloc] = float2{m_s[tile], l_s[tile]};
    }
}

// ---------------------------------------------------------------------------
// attn_merge: combine the two split-K partials per query row, write Cb (bf16).
// 512 blocks = (s,p); 256 threads: 2 threads per row (128 rows), 32 d each.
// ---------------------------------------------------------------------------
__global__ __launch_bounds__(256) void attn_merge(
    const ushortT* __restrict__ OP, const float2* __restrict__ ML,
    ushortT* __restrict__ Cb)
{
    const int bid = blockIdx.x;            // s*16 + p
    const int s = bid >> 4, p = bid & 15;
    const int bb = s >> 4, g = (s >> 3) & 1, mh = s & 7;
    const size_t baseoff = (size_t)bb * 2048 * 1024 + (size_t)g * 512;
    const int t = threadIdx.x;
    const int row = t >> 1;                // 0..127
    const int hd = (t & 1) * 32;
    const int tile = row >> 6, rloc = row & 63;
    const int qt = tile ? (31 - p) : p;
    const float KL = 0.125f * 1.44269504f;
    const int slot0 = bid << 1;
    const float2 ml0 = ML[(size_t)slot0 * 128 + row];
    const float2 ml1 = ML[(size_t)(slot0 + 1) * 128 + row];
    const float m = fmaxf(ml0.x, ml1.x);
    const float a0 = exp2f((ml0.x - m) * KL);
    const float a1 = exp2f((ml1.x - m) * KL);
    const float inv = 1.0f / (ml0.y * a0 + ml1.y * a1);
    const float f0 = a0 * inv, f1 = a1 * inv;
    const ushortT* p0 = OP + (size_t)slot0 * 8192 + (size_t)row * 64 + hd;
    const ushortT* p1 = p0 + 8192;
    const int i = mh * 2048 + qt * 64 + rloc;
    ushortT* dst = Cb + baseoff + (size_t)(i >> 3) * 1024 + (i & 7) * 64 + hd;
    #pragma unroll
    for (int j = 0; j < 32; j += 2) {
        const float v0 = bf2f(p0[j]) * f0 + bf2f(p1[j]) * f1;
        const float v1 = bf2f(p0[j + 1]) * f0 + bf2f(p1[j + 1]) * f1;
        *(__hip_bfloat162*)(dst + j) = __float22bfloat162_rn(float2{v0, v1});
    }
}

extern "C" void kernel_launch(void* const* d_in, const int* in_sizes, int n_in,
                              void* d_out, int out_size, void* d_ws, size_t ws_size,
                              hipStream_t stream)
{
    const float* x  = (const float*)d_in[0];
    const float* Wq = (const float*)d_in[1];
    const float* bq = (const float*)d_in[2];
    const float* Wk = (const float*)d_in[3];
    const float* bk = (const float*)d_in[4];
    const float* Wv = (const float*)d_in[5];
    const float* bv = (const float*)d_in[6];
    const float* Wo = (const float*)d_in[7];
    const float* bo = (const float*)d_in[8];

    const size_t M1 = (size_t)1024 * 1024;
    ushortT* Wb  = (ushortT*)d_ws;            // Wq|Wk|Wv|Wo bf16, 8 MB
    ushortT* xb  = Wb + 4 * M1;               // 8 MB; reused as VT after QKV
    ushortT* Qb  = xb + 4 * M1;               // 8 MB; reused as Cb
    ushortT* Kb  = Qb + 4 * M1;               // 8 MB
    ushortT* Vb  = (ushortT*)d_out;           // V scratch (dead after transpose_v)
    ushortT* VTb = xb;
    ushortT* Cb  = Qb;
    ushortT* OP  = (ushortT*)d_out;           // O partials: 1024 slots x 16 KB = 16 MB
    float2*  ML  = (float2*)Wb;               // m/l partials in dead Wq region (1 MB)

    dim3 blk(256);
    cvt_bf16<<<dim3(4096), blk, 0, stream>>>(x, Wq, Wk, Wv, Wo, xb, Wb);
    gemm_lds<false><<<dim3(24, 32), blk, 0, stream>>>(
        xb, Wb, bq, bk, bv, Qb, Kb, Vb);
    transpose_v<<<dim3(1024), blk, 0, stream>>>(Vb, VTb);
    attn<<<dim3(1024), blk, 0, stream>>>(Qb, Kb, VTb, OP, ML);
    attn_merge<<<dim3(512), blk, 0, stream>>>(OP, ML, Cb);
    gemm_lds<true><<<dim3(8, 32), blk, 0, stream>>>(
        Cb, Wb + 3 * M1, bo, bo, bo, d_out, d_out, d_out);
}